// Round 5
// baseline (163.216 us; speedup 1.0000x reference)
//
#include <hip/hip_runtime.h>

constexpr int T = 128;
constexpr int L = 9;
constexpr float LOG2E = 1.4426950408889634f;
constexpr float LN2   = 0.6931471805599453f;

__device__ __forceinline__ float fexp2(float x) {
    float r; asm("v_exp_f32 %0, %1" : "=v"(r) : "v"(x)); return r;
}
__device__ __forceinline__ float flog2(float x) {
    float r; asm("v_log_f32 %0, %1" : "=v"(r) : "v"(x)); return r;
}

__device__ __forceinline__ float getf(const float4 (&lv)[9], int idx) {
    const float4 q = lv[idx >> 2];
    const int c = idx & 3;
    return c == 0 ? q.x : c == 1 ? q.y : c == 2 ? q.z : q.w;
}

// 9-way register select, constant-indexed (no scratch): 4 cmp + 8 cndmask
__device__ __forceinline__ float sel9(const float (&lg)[9], int lab) {
    const float a0 = (lab & 1) ? lg[1] : lg[0];
    const float a1 = (lab & 1) ? lg[3] : lg[2];
    const float a2 = (lab & 1) ? lg[5] : lg[4];
    const float a3 = (lab & 1) ? lg[7] : lg[6];
    const float b0 = (lab & 2) ? a1 : a0;
    const float b1 = (lab & 2) ? a3 : a2;
    const float c0 = (lab & 4) ? b1 : b0;
    return (lab & 8) ? lg[8] : c0;
}

__device__ __forceinline__ void load_blk(float4 (&lv)[9], int4& labc,
                                         const float* gRow, const int* gLab, int bk)
{
    const float4* p = reinterpret_cast<const float4*>(gRow + bk * 36);
#pragma unroll
    for (int q = 0; q < 9; ++q) lv[q] = p[q];
    labc = *reinterpret_cast<const int4*>(gLab + bk * 4);
}

// one recurrence step (t >= 1)
__device__ __forceinline__ void step_t(bool upd, const float (&lg)[9], float usel, float bsel,
                                       float (&a)[9], float& unary, float& binary,
                                       const float (&et)[81])
{
    float el[9];
#pragma unroll
    for (int j = 0; j < 9; ++j) el[j] = fexp2(lg[j] * LOG2E);
    float s[9];
#pragma unroll
    for (int j = 0; j < 9; ++j) s[j] = a[0] * et[j];
#pragma unroll
    for (int i = 1; i < 9; ++i)
#pragma unroll
        for (int j = 0; j < 9; ++j)
            s[j] = fmaf(a[i], et[i * 9 + j], s[j]);
#pragma unroll
    for (int j = 0; j < 9; ++j) a[j] = upd ? s[j] * el[j] : a[j];
    unary  += upd ? usel : 0.0f;
    binary += upd ? bsel : 0.0f;
}

template <bool FIRSTBLK>
__device__ __forceinline__ void compute4(const float4 (&lv)[9], const int4& labc, int t0,
                                         float (&a)[9], float& unary, float& binary,
                                         int& E, int& plab, const float (&et)[81],
                                         const float* sTrans, int len)
{
    const int labs[4] = {labc.x, labc.y, labc.z, labc.w};
#pragma unroll
    for (int tt = 0; tt < 4; ++tt) {
        const int t = t0 + tt;
        float lg[9];
#pragma unroll
        for (int j = 0; j < 9; ++j) lg[j] = getf(lv, tt * 9 + j);
        const int lab = labs[tt];
        const float usel = sel9(lg, lab);            // register select, no memory
        const float bsel = sTrans[plab * 9 + lab];   // LDS gather (81-entry table)
        const bool upd = t < len;
        if (FIRSTBLK && tt == 0) {
            // t = 0 init: alphas = logits[:,0,:]  (len >= 1 always)
#pragma unroll
            for (int j = 0; j < 9; ++j) a[j] = fexp2(lg[j] * LOG2E);
            unary = usel;
        } else {
            step_t(upd, lg, usel, bsel, a, unary, binary, et);
        }
        plab = lab;
    }
    // exponent rescale once per 4 steps (exact: a *= 2^-k, E += k)
    const unsigned ua = __float_as_uint(a[0]);
    const int k = (int)(ua >> 23) - 127;
    const float sc = __uint_as_float((254u - (ua >> 23)) << 23);
#pragma unroll
    for (int j = 0; j < 9; ++j) a[j] *= sc;
    E += k;
}

__global__ void __launch_bounds__(64)
__attribute__((amdgpu_waves_per_eu(1, 1)))
crf_kernel(const float* __restrict__ logits,
           const int* __restrict__ labels,
           const int* __restrict__ seq_lens,
           const float* __restrict__ trans,
           float* __restrict__ out)
{
    __shared__ float sTrans[81];
    const int lane = threadIdx.x;
    const int b = blockIdx.x * 64 + lane;

    for (int i = lane; i < 81; i += 64) sTrans[i] = trans[i];
    __syncthreads();

    // e^trans table, uniform across lanes, in VGPRs (full budget: waves_per_eu(1,1))
    float et[81];
#pragma unroll
    for (int i = 0; i < 81; ++i) et[i] = fexp2(sTrans[i] * LOG2E);

    const int len = seq_lens[b];
    const float* gRow = logits + (long)b * (T * L);
    const int*   gLab = labels + (long)b * T;

    int maxlen = len;
#pragma unroll
    for (int off = 32; off > 0; off >>= 1)
        maxlen = max(maxlen, __shfl_xor(maxlen, off, 64));

    float a[9];
    float unary = 0.f, binary = 0.f;
    int E = 0, plab = 0;

    float4 bufA[9], bufB[9];
    int4 labA, labB;

    load_blk(bufA, labA, gRow, gLab, 0);
    load_blk(bufB, labB, gRow, gLab, 1);
    compute4<true>(bufA, labA, 0, a, unary, binary, E, plab, et, sTrans, len);

    // blocks 1..30 in pairs (15 iterations), block 31 peeled after
#pragma unroll 1
    for (int i = 1; i < 31; i += 2) {
        if (i * 4 >= maxlen) break;  // wave-uniform early exit
        load_blk(bufA, labA, gRow, gLab, i + 1);
        compute4<false>(bufB, labB, i * 4, a, unary, binary, E, plab, et, sTrans, len);
        load_blk(bufB, labB, gRow, gLab, i + 2);
        compute4<false>(bufA, labA, (i + 1) * 4, a, unary, binary, E, plab, et, sTrans, len);
    }
    if (124 < maxlen)
        compute4<false>(bufB, labB, 124, a, unary, binary, E, plab, et, sTrans, len);

    // log_norm = ln2 * (log2(sum a) + E); nll = log_norm - unary - binary
    float ssum = a[0];
#pragma unroll
    for (int j = 1; j < 9; ++j) ssum += a[j];
    float nll = LN2 * (flog2(ssum) + (float)E) - unary - binary;

#pragma unroll
    for (int off = 32; off > 0; off >>= 1) nll += __shfl_down(nll, off, 64);
    if (lane == 0) atomicAdd(out, nll);
}

extern "C" void kernel_launch(void* const* d_in, const int* in_sizes, int n_in,
                              void* d_out, int out_size, void* d_ws, size_t ws_size,
                              hipStream_t stream)
{
    const float* logits   = (const float*)d_in[0];
    const int*   labels   = (const int*)d_in[1];
    const int*   seq_lens = (const int*)d_in[2];
    const float* trans    = (const float*)d_in[3];
    float* out = (float*)d_out;

    const int B = in_sizes[2];           // 16384
    hipMemsetAsync(d_out, 0, sizeof(float), stream);
    crf_kernel<<<dim3(B / 64), dim3(64), 0, stream>>>(logits, labels, seq_lens, trans, out);
}

// Round 8
// 153.225 us; speedup vs baseline: 1.0652x; 1.0652x over previous
//
#include <hip/hip_runtime.h>

constexpr int T = 128;
constexpr int L = 9;
constexpr float LOG2E = 1.4426950408889634f;
constexpr float LN2   = 0.6931471805599453f;

__device__ __forceinline__ float fexp2(float x){float r;asm("v_exp_f32 %0, %1":"=v"(r):"v"(x));return r;}
__device__ __forceinline__ float flog2(float x){float r;asm("v_log_f32 %0, %1":"=v"(r):"v"(x));return r;}

// ---------- named-scalar machinery: ZERO local arrays, nothing for PromoteAlloca to demote ----------
#define DO_ROW(M,i) M(i,0) M(i,1) M(i,2) M(i,3) M(i,4) M(i,5) M(i,6) M(i,7) M(i,8)
#define DO_ALL(M) DO_ROW(M,0) DO_ROW(M,1) DO_ROW(M,2) DO_ROW(M,3) DO_ROW(M,4) DO_ROW(M,5) DO_ROW(M,6) DO_ROW(M,7) DO_ROW(M,8)
#define REP9(M) M(0) M(1) M(2) M(3) M(4) M(5) M(6) M(7) M(8)

#define DECL_ET(i,j) float et_##i##_##j;
#define INIT_ET(i,j) et_##i##_##j = fexp2(sTrans[(i)*9+(j)] * LOG2E);

#define DECLQ(B,i0,i1,i2,i3) float B##_##i0, B##_##i1, B##_##i2, B##_##i3;
#define DECL_BUF(B) DECLQ(B,0,1,2,3) DECLQ(B,4,5,6,7) DECLQ(B,8,9,10,11) \
  DECLQ(B,12,13,14,15) DECLQ(B,16,17,18,19) DECLQ(B,20,21,22,23) \
  DECLQ(B,24,25,26,27) DECLQ(B,28,29,30,31) DECLQ(B,32,33,34,35)

#define LOADQ(B,q,i0,i1,i2,i3) { const float4 t_ = p_[q]; B##_##i0=t_.x; B##_##i1=t_.y; B##_##i2=t_.z; B##_##i3=t_.w; }
#define LOAD_BLK(B,bk,LABV) { const float4* p_ = reinterpret_cast<const float4*>(gRow + (bk)*36); \
  LOADQ(B,0,0,1,2,3) LOADQ(B,1,4,5,6,7) LOADQ(B,2,8,9,10,11) \
  LOADQ(B,3,12,13,14,15) LOADQ(B,4,16,17,18,19) LOADQ(B,5,20,21,22,23) \
  LOADQ(B,6,24,25,26,27) LOADQ(B,7,28,29,30,31) LOADQ(B,8,32,33,34,35) \
  LABV = *reinterpret_cast<const int4*>(gLab + (bk)*4); }

#define LGS(B,O0,O1,O2,O3,O4,O5,O6,O7,O8) \
  const float lg_0=B##_##O0, lg_1=B##_##O1, lg_2=B##_##O2, lg_3=B##_##O3, lg_4=B##_##O4, \
              lg_5=B##_##O5, lg_6=B##_##O6, lg_7=B##_##O7, lg_8=B##_##O8;

// 9-way register select of lg[lab]: 8 cndmask, constant tree
#define USEL const float x0_=(lab_&1)?lg_1:lg_0, x1_=(lab_&1)?lg_3:lg_2, x2_=(lab_&1)?lg_5:lg_4, x3_=(lab_&1)?lg_7:lg_6; \
  const float y0_=(lab_&2)?x1_:x0_, y1_=(lab_&2)?x3_:x2_; \
  const float z0_=(lab_&4)?y1_:y0_; \
  const float usel_=(lab_&8)?lg_8:z0_;

#define EXPJ(j) const float el_##j = fexp2(lg_##j * LOG2E);
#define MACC(j) float s_##j = a_0*et_0_##j; \
  s_##j=fmaf(a_1,et_1_##j,s_##j); s_##j=fmaf(a_2,et_2_##j,s_##j); s_##j=fmaf(a_3,et_3_##j,s_##j); \
  s_##j=fmaf(a_4,et_4_##j,s_##j); s_##j=fmaf(a_5,et_5_##j,s_##j); s_##j=fmaf(a_6,et_6_##j,s_##j); \
  s_##j=fmaf(a_7,et_7_##j,s_##j); s_##j=fmaf(a_8,et_8_##j,s_##j);
#define AUPD(j) a_##j = upd_ ? s_##j*el_##j : a_##j;

#define STEP_T(B,O0,O1,O2,O3,O4,O5,O6,O7,O8,LAB,UPDEXPR) { \
  const int lab_ = (LAB); const bool upd_ = (UPDEXPR); \
  LGS(B,O0,O1,O2,O3,O4,O5,O6,O7,O8) \
  USEL \
  const float bsel_ = sTrans[plab*9+lab_]; \
  REP9(EXPJ) \
  REP9(MACC) \
  REP9(AUPD) \
  unary  += upd_ ? usel_ : 0.0f; \
  binary += upd_ ? bsel_ : 0.0f; \
  plab = lab_; }

#define STEP_FIRST(B,LAB) { \
  const int lab_ = (LAB); \
  LGS(B,0,1,2,3,4,5,6,7,8) \
  USEL \
  a_0=fexp2(lg_0*LOG2E); a_1=fexp2(lg_1*LOG2E); a_2=fexp2(lg_2*LOG2E); \
  a_3=fexp2(lg_3*LOG2E); a_4=fexp2(lg_4*LOG2E); a_5=fexp2(lg_5*LOG2E); \
  a_6=fexp2(lg_6*LOG2E); a_7=fexp2(lg_7*LOG2E); a_8=fexp2(lg_8*LOG2E); \
  unary += usel_; plab = lab_; }

// exact power-of-two renorm every 4 steps: a *= 2^-k, E += k
#define RESCALE { const unsigned ua_=__float_as_uint(a_0); const int k_=(int)(ua_>>23)-127; \
  const float sc_=__uint_as_float((254u-(ua_>>23))<<23); \
  a_0*=sc_; a_1*=sc_; a_2*=sc_; a_3*=sc_; a_4*=sc_; a_5*=sc_; a_6*=sc_; a_7*=sc_; a_8*=sc_; E+=k_; }

#define COMPUTE4(B,LABV,T0) \
  STEP_T(B,0,1,2,3,4,5,6,7,8,(LABV).x,(((T0)+0)<len)) \
  STEP_T(B,9,10,11,12,13,14,15,16,17,(LABV).y,(((T0)+1)<len)) \
  STEP_T(B,18,19,20,21,22,23,24,25,26,(LABV).z,(((T0)+2)<len)) \
  STEP_T(B,27,28,29,30,31,32,33,34,35,(LABV).w,(((T0)+3)<len)) \
  RESCALE

#define COMPUTE4_FIRST(B,LABV) \
  STEP_FIRST(B,(LABV).x) \
  STEP_T(B,9,10,11,12,13,14,15,16,17,(LABV).y,(1<len)) \
  STEP_T(B,18,19,20,21,22,23,24,25,26,(LABV).z,(2<len)) \
  STEP_T(B,27,28,29,30,31,32,33,34,35,(LABV).w,(3<len)) \
  RESCALE

__global__ void __launch_bounds__(64, 1)
crf_kernel(const float* __restrict__ logits,
           const int* __restrict__ labels,
           const int* __restrict__ seq_lens,
           const float* __restrict__ trans,
           float* __restrict__ out)
{
    __shared__ float sTrans[81];
    const int lane = threadIdx.x;
    const int b = blockIdx.x * 64 + lane;

    for (int i = lane; i < 81; i += 64) sTrans[i] = trans[i];
    __syncthreads();

    DO_ALL(DECL_ET)
    DO_ALL(INIT_ET)

    const int len = seq_lens[b];
    const float* gRow = logits + (long)b * (T * L);
    const int*   gLab = labels + (long)b * T;

    int maxlen = len;
#pragma unroll
    for (int off = 32; off > 0; off >>= 1)
        maxlen = max(maxlen, __shfl_xor(maxlen, off, 64));

    float a_0=0.f,a_1=0.f,a_2=0.f,a_3=0.f,a_4=0.f,a_5=0.f,a_6=0.f,a_7=0.f,a_8=0.f;
    float unary = 0.f, binary = 0.f;
    int E = 0, plab = 0;

    DECL_BUF(bufA)
    DECL_BUF(bufB)
    int4 labA, labB;

    LOAD_BLK(bufA,0,labA);
    LOAD_BLK(bufB,1,labB);
    COMPUTE4_FIRST(bufA,labA);

    // blocks 1..30 in pairs, block 31 peeled after
#pragma unroll 1
    for (int i = 1; i < 31; i += 2) {
        if (i * 4 >= maxlen) break;  // wave-uniform early exit
        LOAD_BLK(bufA,i+1,labA);
        COMPUTE4(bufB,labB,i*4);
        LOAD_BLK(bufB,i+2,labB);
        COMPUTE4(bufA,labA,(i+1)*4);
    }
    if (124 < maxlen)
        COMPUTE4(bufB,labB,124);

    // log_norm = ln2*(log2(sum a) + E); nll = log_norm - unary - binary
    const float ssum = a_0+a_1+a_2+a_3+a_4+a_5+a_6+a_7+a_8;
    float nll = LN2 * (flog2(ssum) + (float)E) - unary - binary;

#pragma unroll
    for (int off = 32; off > 0; off >>= 1) nll += __shfl_down(nll, off, 64);
    if (lane == 0) atomicAdd(out, nll);
}

extern "C" void kernel_launch(void* const* d_in, const int* in_sizes, int n_in,
                              void* d_out, int out_size, void* d_ws, size_t ws_size,
                              hipStream_t stream)
{
    const float* logits   = (const float*)d_in[0];
    const int*   labels   = (const int*)d_in[1];
    const int*   seq_lens = (const int*)d_in[2];
    const float* trans    = (const float*)d_in[3];
    float* out = (float*)d_out;

    const int B = in_sizes[2];           // 16384
    hipMemsetAsync(d_out, 0, sizeof(float), stream);
    crf_kernel<<<dim3(B / 64), dim3(64), 0, stream>>>(logits, labels, seq_lens, trans, out);
}

// Round 10
// 151.771 us; speedup vs baseline: 1.0754x; 1.0096x over previous
//
#include <hip/hip_runtime.h>

constexpr int T = 128;
constexpr int L = 9;
constexpr float LOG2E = 1.4426950408889634f;
constexpr float LN2   = 0.6931471805599453f;

__device__ __forceinline__ float fexp2(float x){float r;asm("v_exp_f32 %0, %1":"=v"(r):"v"(x));return r;}
__device__ __forceinline__ float flog2(float x){float r;asm("v_log_f32 %0, %1":"=v"(r):"v"(x));return r;}

// ---------- named-scalar machinery: zero local arrays ----------
#define DO_ROW(M,i) M(i,0) M(i,1) M(i,2) M(i,3) M(i,4) M(i,5) M(i,6) M(i,7) M(i,8)
#define DO_ALL(M) DO_ROW(M,0) DO_ROW(M,1) DO_ROW(M,2) DO_ROW(M,3) DO_ROW(M,4) DO_ROW(M,5) DO_ROW(M,6) DO_ROW(M,7) DO_ROW(M,8)
#define REP9(M) M(0) M(1) M(2) M(3) M(4) M(5) M(6) M(7) M(8)

// et is WAVE-UNIFORM: force SGPR class via readfirstlane so the 81-entry
// table costs zero VGPRs (v_fma reads it as the single allowed SGPR operand).
#define DECL_ET(i,j) float et_##i##_##j;
#define INIT_ET(i,j) et_##i##_##j = __int_as_float(__builtin_amdgcn_readfirstlane(__float_as_int(fexp2(trans[(i)*9+(j)] * LOG2E))));

#define DECLQ(B,i0,i1,i2,i3) float B##_##i0, B##_##i1, B##_##i2, B##_##i3;
#define DECL_BUF(B) DECLQ(B,0,1,2,3) DECLQ(B,4,5,6,7) DECLQ(B,8,9,10,11) \
  DECLQ(B,12,13,14,15) DECLQ(B,16,17,18,19) DECLQ(B,20,21,22,23) \
  DECLQ(B,24,25,26,27) DECLQ(B,28,29,30,31) DECLQ(B,32,33,34,35)

#define LOADQ(B,q,i0,i1,i2,i3) { const float4 t_ = p_[q]; B##_##i0=t_.x; B##_##i1=t_.y; B##_##i2=t_.z; B##_##i3=t_.w; }
#define LOAD_BLK(B,bk,LABV) { const float4* p_ = reinterpret_cast<const float4*>(gRow + (bk)*36); \
  LOADQ(B,0,0,1,2,3) LOADQ(B,1,4,5,6,7) LOADQ(B,2,8,9,10,11) \
  LOADQ(B,3,12,13,14,15) LOADQ(B,4,16,17,18,19) LOADQ(B,5,20,21,22,23) \
  LOADQ(B,6,24,25,26,27) LOADQ(B,7,28,29,30,31) LOADQ(B,8,32,33,34,35) \
  LABV = *reinterpret_cast<const int4*>(gLab + (bk)*4); }

#define LGS(B,O0,O1,O2,O3,O4,O5,O6,O7,O8) \
  const float lg_0=B##_##O0, lg_1=B##_##O1, lg_2=B##_##O2, lg_3=B##_##O3, lg_4=B##_##O4, \
              lg_5=B##_##O5, lg_6=B##_##O6, lg_7=B##_##O7, lg_8=B##_##O8;

// 9-way register select of lg[lab]: 8 cndmask, constant tree
#define USEL const float x0_=(lab_&1)?lg_1:lg_0, x1_=(lab_&1)?lg_3:lg_2, x2_=(lab_&1)?lg_5:lg_4, x3_=(lab_&1)?lg_7:lg_6; \
  const float y0_=(lab_&2)?x1_:x0_, y1_=(lab_&2)?x3_:x2_; \
  const float z0_=(lab_&4)?y1_:y0_; \
  const float usel_=(lab_&8)?lg_8:z0_;

#define EXPJ(j) const float el_##j = fexp2(lg_##j * LOG2E);
#define MACC(j) float s_##j = a_0*et_0_##j; \
  s_##j=fmaf(a_1,et_1_##j,s_##j); s_##j=fmaf(a_2,et_2_##j,s_##j); s_##j=fmaf(a_3,et_3_##j,s_##j); \
  s_##j=fmaf(a_4,et_4_##j,s_##j); s_##j=fmaf(a_5,et_5_##j,s_##j); s_##j=fmaf(a_6,et_6_##j,s_##j); \
  s_##j=fmaf(a_7,et_7_##j,s_##j); s_##j=fmaf(a_8,et_8_##j,s_##j);
#define AUPD(j) a_##j = upd_ ? s_##j*el_##j : a_##j;

// bsel passed in (hoisted per-block so the 4 ds_reads overlap)
#define STEP_T(B,O0,O1,O2,O3,O4,O5,O6,O7,O8,LAB,BSEL,UPDEXPR) { \
  const int lab_ = (LAB); const bool upd_ = (UPDEXPR); \
  LGS(B,O0,O1,O2,O3,O4,O5,O6,O7,O8) \
  USEL \
  REP9(EXPJ) \
  REP9(MACC) \
  REP9(AUPD) \
  unary  += upd_ ? usel_ : 0.0f; \
  binary += upd_ ? (BSEL) : 0.0f; }

#define STEP_FIRST(B,LAB) { \
  const int lab_ = (LAB); \
  LGS(B,0,1,2,3,4,5,6,7,8) \
  USEL \
  a_0=fexp2(lg_0*LOG2E); a_1=fexp2(lg_1*LOG2E); a_2=fexp2(lg_2*LOG2E); \
  a_3=fexp2(lg_3*LOG2E); a_4=fexp2(lg_4*LOG2E); a_5=fexp2(lg_5*LOG2E); \
  a_6=fexp2(lg_6*LOG2E); a_7=fexp2(lg_7*LOG2E); a_8=fexp2(lg_8*LOG2E); \
  unary += usel_; }

// exact power-of-two renorm every 4 steps: a *= 2^-k, E += k
#define RESCALE { const unsigned ua_=__float_as_uint(a_0); const int k_=(int)(ua_>>23)-127; \
  const float sc_=__uint_as_float((254u-(ua_>>23))<<23); \
  a_0*=sc_; a_1*=sc_; a_2*=sc_; a_3*=sc_; a_4*=sc_; a_5*=sc_; a_6*=sc_; a_7*=sc_; a_8*=sc_; E+=k_; }

#define COMPUTE4(B,LABV,T0) { \
  const int l0_=(LABV).x, l1_=(LABV).y, l2_=(LABV).z, l3_=(LABV).w; \
  const float bs0_=sTrans[plab*9+l0_], bs1_=sTrans[l0_*9+l1_], bs2_=sTrans[l1_*9+l2_], bs3_=sTrans[l2_*9+l3_]; \
  STEP_T(B,0,1,2,3,4,5,6,7,8,l0_,bs0_,(((T0)+0)<len)) \
  STEP_T(B,9,10,11,12,13,14,15,16,17,l1_,bs1_,(((T0)+1)<len)) \
  STEP_T(B,18,19,20,21,22,23,24,25,26,l2_,bs2_,(((T0)+2)<len)) \
  STEP_T(B,27,28,29,30,31,32,33,34,35,l3_,bs3_,(((T0)+3)<len)) \
  plab = l3_; \
  RESCALE }

#define COMPUTE4_FIRST(B,LABV) { \
  const int l0_=(LABV).x, l1_=(LABV).y, l2_=(LABV).z, l3_=(LABV).w; \
  const float bs1_=sTrans[l0_*9+l1_], bs2_=sTrans[l1_*9+l2_], bs3_=sTrans[l2_*9+l3_]; \
  STEP_FIRST(B,l0_) \
  STEP_T(B,9,10,11,12,13,14,15,16,17,l1_,bs1_,(1<len)) \
  STEP_T(B,18,19,20,21,22,23,24,25,26,l2_,bs2_,(2<len)) \
  STEP_T(B,27,28,29,30,31,32,33,34,35,l3_,bs3_,(3<len)) \
  plab = l3_; \
  RESCALE }

__global__ void __launch_bounds__(64, 1)
crf_kernel(const float* __restrict__ logits,
           const int* __restrict__ labels,
           const int* __restrict__ seq_lens,
           const float* __restrict__ trans,
           float* __restrict__ out)
{
    __shared__ float sTrans[81];
    const int lane = threadIdx.x;
    const int b = blockIdx.x * 64 + lane;

    for (int i = lane; i < 81; i += 64) sTrans[i] = trans[i];
    __syncthreads();

    DO_ALL(DECL_ET)
    DO_ALL(INIT_ET)

    const int len = seq_lens[b];
    const float* gRow = logits + (long)b * (T * L);
    const int*   gLab = labels + (long)b * T;

    int maxlen = len;
#pragma unroll
    for (int off = 32; off > 0; off >>= 1)
        maxlen = max(maxlen, __shfl_xor(maxlen, off, 64));

    float a_0=0.f,a_1=0.f,a_2=0.f,a_3=0.f,a_4=0.f,a_5=0.f,a_6=0.f,a_7=0.f,a_8=0.f;
    float unary = 0.f, binary = 0.f;
    int E = 0, plab = 0;

    DECL_BUF(bufA)
    DECL_BUF(bufB)
    int4 labA, labB;

    LOAD_BLK(bufA,0,labA);
    LOAD_BLK(bufB,1,labB);
    COMPUTE4_FIRST(bufA,labA);

    // blocks 1..30 in pairs, block 31 peeled after
#pragma unroll 1
    for (int i = 1; i < 31; i += 2) {
        if (i * 4 >= maxlen) break;  // wave-uniform early exit
        LOAD_BLK(bufA,i+1,labA);
        COMPUTE4(bufB,labB,i*4);
        LOAD_BLK(bufB,i+2,labB);
        COMPUTE4(bufA,labA,(i+1)*4);
    }
    if (124 < maxlen)
        COMPUTE4(bufB,labB,124);

    // log_norm = ln2*(log2(sum a) + E); nll = log_norm - unary - binary
    const float ssum = a_0+a_1+a_2+a_3+a_4+a_5+a_6+a_7+a_8;
    float nll = LN2 * (flog2(ssum) + (float)E) - unary - binary;

#pragma unroll
    for (int off = 32; off > 0; off >>= 1) nll += __shfl_down(nll, off, 64);
    if (lane == 0) atomicAdd(out, nll);
}

extern "C" void kernel_launch(void* const* d_in, const int* in_sizes, int n_in,
                              void* d_out, int out_size, void* d_ws, size_t ws_size,
                              hipStream_t stream)
{
    const float* logits   = (const float*)d_in[0];
    const int*   labels   = (const int*)d_in[1];
    const int*   seq_lens = (const int*)d_in[2];
    const float* trans    = (const float*)d_in[3];
    float* out = (float*)d_out;

    const int B = in_sizes[2];           // 16384
    hipMemsetAsync(d_out, 0, sizeof(float), stream);
    crf_kernel<<<dim3(B / 64), dim3(64), 0, stream>>>(logits, labels, seq_lens, trans, out);
}